// Round 3
// baseline (276.128 us; speedup 1.0000x reference)
//
#include <hip/hip_runtime.h>

// Problem constants: B=4, SEQ=4096, D=64, BS=32, V=512, R=128, P=33024
#define Bn   4
#define SEQn 4096
#define Dn   64
#define BSn  32
#define Vn   512
#define Rn   128
#define PPB  8256   // p's per batch = R*(R+1)/2

// Fused kernel: one block per (batch b, row-pair {r, 127-r}).
// 256 blocks x 1024 threads, 1 block/CU, perfectly balanced:
// every block computes 2 score-slabs (32x512, K=64) in LDS and gathers
// exactly (r+1)+(128-r) = 129 p's = 516 KB of output.
// Eliminates the scores workspace (32 MiB write + 80 MiB re-read), the
// separate GEMM dispatch, and the inter-kernel dependency.

#define SEP  258   // se word stride per d-row (256 + 2 pad, float2-aligned)
#define QWS  68    // sq word stride per row (64 + 4, float4-aligned)

// load info batch for iteration-group base itb into named int4 regs
#define LOADI(R0, R1, R2, R3, itb)                                        \
  {                                                                       \
    int p0_ = ((itb) + 0) * 4 + sub, p1_ = ((itb) + 1) * 4 + sub;         \
    int p2_ = ((itb) + 2) * 4 + sub, p3_ = ((itb) + 3) * 4 + sub;         \
    R0 = info4[(base + (size_t)(p0_ <= r ? p0_ : 0)) * 256 + t];          \
    R1 = info4[(base + (size_t)(p1_ <= r ? p1_ : 0)) * 256 + t];          \
    R2 = info4[(base + (size_t)(p2_ <= r ? p2_ : 0)) * 256 + t];          \
    R3 = info4[(base + (size_t)(p3_ <= r ? p3_ : 0)) * 256 + t];          \
  }

#define PROC1(RV, pp)                                                     \
  if ((pp) <= r) {                                                        \
    float4 o_;                                                            \
    o_.x = slab[rowoff + RV.x];                                           \
    o_.y = slab[rowoff + RV.y];                                           \
    o_.z = slab[rowoff + RV.z];                                           \
    o_.w = slab[rowoff + RV.w];                                           \
    out4[(base + (size_t)(pp)) * 256 + t] = o_;                           \
  }

#define PROCI(R0, R1, R2, R3, itb)                                        \
  {                                                                       \
    PROC1(R0, ((itb) + 0) * 4 + sub);                                     \
    PROC1(R1, ((itb) + 1) * 4 + sub);                                     \
    PROC1(R2, ((itb) + 2) * 4 + sub);                                     \
    PROC1(R3, ((itb) + 3) * 4 + sub);                                     \
  }

__global__ __launch_bounds__(1024, 4) void fused_kernel(
    const float* __restrict__ q, const float* __restrict__ emb,
    const int* __restrict__ info, float* __restrict__ out)
{
  __shared__ float sq[32 * QWS];     // 8.5 KB  [row][d]
  __shared__ float se[Dn * SEP];     // 64.5 KB [d][v'] — half of emb, transposed
  __shared__ float slab[BSn * Vn];   // 64 KB   [i][v]

  const int pair = blockIdx.x;   // 0..63
  const int b    = blockIdx.y;   // 0..3
  const int tid  = threadIdx.x;

  // gather mapping (4 p's in parallel)
  const int sub    = tid >> 8;           // 0..3
  const int t      = tid & 255;          // slot within a p
  const int rowoff = (t >> 3) << 9;      // slab row (t>>3) * 512

  // gemm mapping: rows rg*4..rg*4+3, float2 column v2 within the v-half
  const int rg = tid >> 7;               // 0..7, wave-uniform
  const int v2 = tid & 127;

  const int4*   info4 = (const int4*)info;
  float4*       out4  = (float4*)out;
  const float2* se2   = (const float2*)se;
  float2*       slab2 = (float2*)slab;

  for (int s = 0; s < 2; ++s) {
    const int r = s ? (127 - pair) : pair;              // 0..63 then 64..127
    const size_t base = (size_t)b * PPB + (((size_t)r * (r + 1)) >> 1);
    const int NIT = (r + 4) >> 2;                       // ceil((r+1)/4)

    // ---- stage q rows [r*32, r*32+32): 512 float4 ----
    if (tid < 512) {
      const float4* qs4 = (const float4*)(q + ((size_t)b * SEQn + (size_t)r * BSn) * Dn);
      float4 x = qs4[tid];
      ((float4*)sq)[(tid >> 4) * (QWS / 4) + (tid & 15)] = x;
    }

    // ---- prefetch info batch A (groups 0..3) — hides under staging+GEMM ----
    int4 A0, A1, A2, A3;
    LOADI(A0, A1, A2, A3, 0);

    for (int hv = 0; hv < 2; ++hv) {
      __syncthreads();   // prev gather/GEMM done -> safe to overwrite se (and q visible)
      // ---- stage emb half hv, transposed to [d][v'] ----
      {
        const float4* es4 = (const float4*)(emb + ((size_t)b * Vn + (size_t)hv * 256) * Dn);
#pragma unroll
        for (int k = 0; k < 4; ++k) {
          int idx = tid + (k << 10);
          float4 x = es4[idx];
          int vp = idx >> 4;
          int d0 = (idx & 15) << 2;
          se[(d0 + 0) * SEP + vp] = x.x;
          se[(d0 + 1) * SEP + vp] = x.y;
          se[(d0 + 2) * SEP + vp] = x.z;
          se[(d0 + 3) * SEP + vp] = x.w;
        }
      }
      __syncthreads();
      // ---- GEMM: slab[rg*4+j][hv*256 + 2*v2 + {0,1}] over d=0..63 ----
      float2 a0 = {0.f, 0.f}, a1 = {0.f, 0.f}, a2 = {0.f, 0.f}, a3 = {0.f, 0.f};
      const float* qb = sq + (rg * 4) * QWS;
#pragma unroll
      for (int d0 = 0; d0 < Dn; d0 += 4) {
        float4 Q0 = *(const float4*)(qb + d0);
        float4 Q1 = *(const float4*)(qb + QWS + d0);
        float4 Q2 = *(const float4*)(qb + 2 * QWS + d0);
        float4 Q3 = *(const float4*)(qb + 3 * QWS + d0);
        float2 e0 = se2[(d0 + 0) * (SEP / 2) + v2];
        float2 e1 = se2[(d0 + 1) * (SEP / 2) + v2];
        float2 e2 = se2[(d0 + 2) * (SEP / 2) + v2];
        float2 e3 = se2[(d0 + 3) * (SEP / 2) + v2];
        a0.x += Q0.x * e0.x; a0.y += Q0.x * e0.y;
        a1.x += Q1.x * e0.x; a1.y += Q1.x * e0.y;
        a2.x += Q2.x * e0.x; a2.y += Q2.x * e0.y;
        a3.x += Q3.x * e0.x; a3.y += Q3.x * e0.y;
        a0.x += Q0.y * e1.x; a0.y += Q0.y * e1.y;
        a1.x += Q1.y * e1.x; a1.y += Q1.y * e1.y;
        a2.x += Q2.y * e1.x; a2.y += Q2.y * e1.y;
        a3.x += Q3.y * e1.x; a3.y += Q3.y * e1.y;
        a0.x += Q0.z * e2.x; a0.y += Q0.z * e2.y;
        a1.x += Q1.z * e2.x; a1.y += Q1.z * e2.y;
        a2.x += Q2.z * e2.x; a2.y += Q2.z * e2.y;
        a3.x += Q3.z * e2.x; a3.y += Q3.z * e2.y;
        a0.x += Q0.w * e3.x; a0.y += Q0.w * e3.y;
        a1.x += Q1.w * e3.x; a1.y += Q1.w * e3.y;
        a2.x += Q2.w * e3.x; a2.y += Q2.w * e3.y;
        a3.x += Q3.w * e3.x; a3.y += Q3.w * e3.y;
      }
      {
        int sb = (rg * 4) * 256 + (hv << 7) + v2;
        slab2[sb]       = a0;
        slab2[sb + 256] = a1;
        slab2[sb + 512] = a2;
        slab2[sb + 768] = a3;
      }
    }
    __syncthreads();   // slab complete

    // ---- gather: NIT groups of 4 p's; A/B double-buffered info prefetch ----
    for (int it0 = 0; it0 < NIT; it0 += 8) {
      int4 B0, B1, B2, B3;
      if (it0 + 4 < NIT) LOADI(B0, B1, B2, B3, it0 + 4);
      PROCI(A0, A1, A2, A3, it0);
      if (it0 + 8 < NIT) LOADI(A0, A1, A2, A3, it0 + 8);
      if (it0 + 4 < NIT) PROCI(B0, B1, B2, B3, it0 + 4);
    }
  }
}

extern "C" void kernel_launch(void* const* d_in, const int* in_sizes, int n_in,
                              void* d_out, int out_size, void* d_ws, size_t ws_size,
                              hipStream_t stream) {
  const float* q    = (const float*)d_in[0];
  const float* emb  = (const float*)d_in[1];
  const int*   info = (const int*)d_in[2];
  // d_in[3]/d_in[4] (idxs_batch/idxs_row) derivable from tril structure.
  float* out = (float*)d_out;
  (void)d_ws; (void)ws_size;   // no workspace needed anymore

  dim3 grid(64, Bn);   // 256 blocks = 1 per CU, each a balanced row-pair
  fused_kernel<<<grid, 1024, 0, stream>>>(q, emb, info, out);
}